// Round 12
// baseline (215.240 us; speedup 1.0000x reference)
//
#include <hip/hip_runtime.h>
#include <hip/hip_fp16.h>
#include <stdint.h>

#define NB 32          // batch size B (fixed by problem)
#define BIN_SHIFT 5    // 32 dst rows per fine bin
#define BIN_ROWS 32
#define NBINS_MAX 4096 // fine bins: supports M <= 131072
#define CSHIFT 8       // 256 dst rows per coarse region (8 fine bins)
#define NC_MAX 512     // coarse regions: supports M <= 131072
#define FPC 8          // fine bins per coarse region
#define NWAVE 16       // waves per 1024-thread block
#define FCHUNK 8192    // edges per coarse-fill block
#define FTHREADS 1024
#define EPT (FCHUNK / FTHREADS)      // 8
#define CAP_C 9216     // region capacity: mean 8192 + 11 sigma
#define EPT2 (CAP_C / FTHREADS)      // 9
#define SRC_BITS 18    // N < 262144 (problem: N = 100000)
#define SRC_MASK ((1u << SRC_BITS) - 1)
#define CAP 1408       // gather LDS sort capacity (fine-bin mean 1024 + 12 sigma)
#define MAXK 6         // ceil(CAP / 256) entries per thread in sort_gather

// meta layout: bits [25:18] = dst & 255, bits [17:0] = src
//   row-in-fine-bin      = (meta >> 18) & 31   (= dst & 31)
//   fine-bin-in-region   = (meta >> 23) & 7    (= (dst >> 5) & 7)

// ---------------------------------------------------------------------------
// x (B, N) f32 -> xt (N, B) f16: 32x32 LDS tile transpose.
// ---------------------------------------------------------------------------
__global__ void transpose_x_kernel(const float* __restrict__ x,
                                   __half* __restrict__ xt, int N) {
    __shared__ float tile[32][33];
    int n0 = blockIdx.x * 32;
    for (int i = threadIdx.y; i < 32; i += 8) {
        int n = n0 + threadIdx.x;
        tile[i][threadIdx.x] = (n < N) ? x[(size_t)i * N + n] : 0.f;
    }
    __syncthreads();
    for (int i = threadIdx.y; i < 32; i += 8) {
        int n = n0 + i;
        if (n < N) xt[(size_t)n * NB + threadIdx.x] =
            __float2half(tile[threadIdx.x][i]);
    }
}

// ---------------------------------------------------------------------------
// Pass 1: coarse radix fill into 256-row regions (runs ~21 edges = 168B).
// Lean: 2 LDS atomics/edge, 4 KB LDS, no fine-histogram work.
// Region overflow (mean+11sigma, statistically never) -> ovList -> fixup.
// ---------------------------------------------------------------------------
__global__ void fill_coarse(const int* __restrict__ src,
                            const int* __restrict__ dst,
                            const float* __restrict__ vals,
                            int* __restrict__ cCursor,   // [NC_MAX], rel, 0-init
                            uint2* __restrict__ cCsr,    // [ncoarse*CAP_C]
                            int* __restrict__ ovCount,
                            int* __restrict__ ovList,
                            int nnz, int ncoarse) {
    __shared__ int lhist[NC_MAX];    // counts, then rank cursors
    __shared__ int lbase[NC_MAX];    // claimed relative bases
    int t = threadIdx.x;
    int e0 = blockIdx.x * FCHUNK;
    int dcache[EPT];
    for (int i = t; i < NC_MAX; i += FTHREADS) lhist[i] = 0;
    __syncthreads();
#pragma unroll
    for (int q = 0; q < EPT; ++q) {
        int e = e0 + q * FTHREADS + t;
        int d = (e < nnz) ? dst[e] : -1;
        dcache[q] = d;
        if (d >= 0) atomicAdd(&lhist[d >> CSHIFT], 1);
    }
    __syncthreads();
    for (int i = t; i < ncoarse; i += FTHREADS) {
        int c = lhist[i];
        lbase[i] = c ? atomicAdd(&cCursor[i], c) : 0;
        lhist[i] = 0;  // reuse as rank cursor
    }
    __syncthreads();
#pragma unroll
    for (int q = 0; q < EPT; ++q) {
        int e = e0 + q * FTHREADS + t;
        int d = dcache[q];
        if (d >= 0) {
            int c = d >> CSHIFT;
            int r = lbase[c] + atomicAdd(&lhist[c], 1);
            if (r < CAP_C) {
                uint32_t meta = ((uint32_t)(d & 255) << SRC_BITS) |
                                (uint32_t)src[e];
                cCsr[(size_t)c * CAP_C + r] =
                    make_uint2(meta, __float_as_uint(vals[e]));
            } else {
                int op = atomicAdd(ovCount, 1);
                ovList[op] = e;   // sized nnz: cannot overflow
            }
        }
    }
}

// ---------------------------------------------------------------------------
// Pass 2 (fused fine-fill + scan): one block per coarse region.
// Reads the region's entries ONCE into registers, builds the EXACT 8-bin
// layout in LDS (per-wave hist -> serial 128-step scan -> per-wave global
// cursors), writes packed-within-region fineCsr + fineBase/fineCnt.
// Fine overflow impossible (region-exact packing). Deletes fine_scan kernel.
// ---------------------------------------------------------------------------
__global__ __launch_bounds__(1024) void fill_fine2(
        const int* __restrict__ cCursor,
        const uint2* __restrict__ cCsr,
        uint2* __restrict__ fineCsr,
        int* __restrict__ fineBase,
        int* __restrict__ fineCnt) {
    __shared__ int whist[NWAVE][FPC];   // counts, then region-rel cursors
    __shared__ int fbase[FPC];
    __shared__ int ftot;
    int c = blockIdx.x;
    int n = min(cCursor[c], CAP_C);
    int t = threadIdx.x;
    int w = t >> 6;                     // wave id 0..15
    uint2 ec[EPT2];
    if (t < NWAVE * FPC) (&whist[0][0])[t] = 0;
    __syncthreads();
    const uint2* reg = cCsr + (size_t)c * CAP_C;
#pragma unroll
    for (int q = 0; q < EPT2; ++q) {
        int j = q * FTHREADS + t;
        if (j < n) {
            uint2 e = reg[j];
            ec[q] = e;
            atomicAdd(&whist[w][(e.x >> 23) & 7], 1);
        }
    }
    __syncthreads();
    if (t == 0) {
        int run = 0;
        for (int f = 0; f < FPC; ++f) {
            fbase[f] = run;
            for (int w2 = 0; w2 < NWAVE; ++w2) {
                int cn = whist[w2][f];
                whist[w2][f] = run;   // region-relative cursor for (wave,f)
                run += cn;
            }
        }
        ftot = run;                   // == n
    }
    __syncthreads();
    if (t < FPC) {
        int gbin = c * FPC + t;
        fineBase[gbin] = c * CAP_C + fbase[t];
        int endv = (t == FPC - 1) ? ftot : fbase[t + 1];
        fineCnt[gbin] = endv - fbase[t];
    }
#pragma unroll
    for (int q = 0; q < EPT2; ++q) {
        int j = q * FTHREADS + t;
        if (j < n) {
            uint2 e = ec[q];
            int p = atomicAdd(&whist[w][(e.x >> 23) & 7], 1);
            fineCsr[(size_t)c * CAP_C + p] = e;
        }
    }
}

// ---------------------------------------------------------------------------
// Fused sort + gather + bias + output-transpose, one block per 32-row fine
// bin (round-11 proven structure):
//  1. read the bin's entries ONCE into registers; LDS counting-sort by row;
//  2. half-wave per row: fp16 xt gather, fp32 acc, 8-deep pipeline;
//  3. direct write to out (B, M) + bias.
// cnt > CAP (adversarial skew only): LDS-atomic-tile slow path.
// ---------------------------------------------------------------------------
__global__ __launch_bounds__(256) void sort_gather(
        const int* __restrict__ fineBase,
        const int* __restrict__ fineCnt,
        const uint2* __restrict__ csr,
        const __half* __restrict__ xt,
        const float* __restrict__ bias,
        float* __restrict__ out, int M) {
    __shared__ uint2 sorted[CAP];      // 11 KB (aliased as tile in slow path)
    __shared__ int rowCnt[BIN_ROWS];
    __shared__ int rowOff[BIN_ROWS];
    int t = threadIdx.x;
    int bin = blockIdx.x;
    int start = fineBase[bin];
    int cnt   = fineCnt[bin];
    int g = t >> 5;   // half-wave id 0..7
    int b = t & 31;   // batch lane

    if (cnt <= CAP) {
        uint2 reg[MAXK];
#pragma unroll
        for (int k = 0; k < MAXK; ++k) {
            int j = t + k * 256;
            if (j < cnt) reg[k] = csr[start + j];
        }
        if (t < BIN_ROWS) rowCnt[t] = 0;
        __syncthreads();
#pragma unroll
        for (int k = 0; k < MAXK; ++k) {
            int j = t + k * 256;
            if (j < cnt)
                atomicAdd(&rowCnt[(reg[k].x >> SRC_BITS) & 31], 1);
        }
        __syncthreads();
        if (t == 0) {
            int run = 0;
#pragma unroll
            for (int r = 0; r < BIN_ROWS; ++r) {
                rowOff[r] = run;
                run += rowCnt[r];
            }
        }
        __syncthreads();
#pragma unroll
        for (int k = 0; k < MAXK; ++k) {
            int j = t + k * 256;
            if (j < cnt) {
                int p = atomicAdd(&rowOff[(reg[k].x >> SRC_BITS) & 31], 1);
                sorted[p] = reg[k];
            }
        }
        __syncthreads();
        for (int r = g; r < BIN_ROWS; r += 8) {
            int m = bin * BIN_ROWS + r;
            if (m >= M) break;
            int jend = rowOff[r];
            int jj   = jend - rowCnt[r];
            float acc0 = 0.f, acc1 = 0.f;
            for (; jj + 8 <= jend; jj += 8) {
                uint2 e0 = sorted[jj + 0];
                uint2 e1 = sorted[jj + 1];
                uint2 e2 = sorted[jj + 2];
                uint2 e3 = sorted[jj + 3];
                uint2 e4 = sorted[jj + 4];
                uint2 e5 = sorted[jj + 5];
                uint2 e6 = sorted[jj + 6];
                uint2 e7 = sorted[jj + 7];
                float x0 = __half2float(xt[(size_t)(e0.x & SRC_MASK) * NB + b]);
                float x1 = __half2float(xt[(size_t)(e1.x & SRC_MASK) * NB + b]);
                float x2 = __half2float(xt[(size_t)(e2.x & SRC_MASK) * NB + b]);
                float x3 = __half2float(xt[(size_t)(e3.x & SRC_MASK) * NB + b]);
                float x4 = __half2float(xt[(size_t)(e4.x & SRC_MASK) * NB + b]);
                float x5 = __half2float(xt[(size_t)(e5.x & SRC_MASK) * NB + b]);
                float x6 = __half2float(xt[(size_t)(e6.x & SRC_MASK) * NB + b]);
                float x7 = __half2float(xt[(size_t)(e7.x & SRC_MASK) * NB + b]);
                acc0 = fmaf(__uint_as_float(e0.y), x0, acc0);
                acc1 = fmaf(__uint_as_float(e1.y), x1, acc1);
                acc0 = fmaf(__uint_as_float(e2.y), x2, acc0);
                acc1 = fmaf(__uint_as_float(e3.y), x3, acc1);
                acc0 = fmaf(__uint_as_float(e4.y), x4, acc0);
                acc1 = fmaf(__uint_as_float(e5.y), x5, acc1);
                acc0 = fmaf(__uint_as_float(e6.y), x6, acc0);
                acc1 = fmaf(__uint_as_float(e7.y), x7, acc1);
            }
            for (; jj < jend; ++jj) {
                uint2 e = sorted[jj];
                acc0 = fmaf(__uint_as_float(e.y),
                            __half2float(xt[(size_t)(e.x & SRC_MASK) * NB + b]),
                            acc0);
            }
            out[(size_t)b * M + m] = acc0 + acc1 + bias[m];
        }
    } else {
        // slow path (arbitrary skew): LDS float-atomic 32x32 tile
        float* tile = (float*)sorted;   // 4 KB alias
        for (int i = t; i < BIN_ROWS * NB; i += 256) tile[i] = 0.f;
        __syncthreads();
        for (int j = start + g; j < start + cnt; j += 8) {
            uint2 e = csr[j];   // broadcast across half-wave
            float xv = __half2float(xt[(size_t)(e.x & SRC_MASK) * NB + b]);
            atomicAdd(&tile[((e.x >> SRC_BITS) & 31) * NB + b],
                      __uint_as_float(e.y) * xv);
        }
        __syncthreads();
        for (int i = t; i < BIN_ROWS * NB; i += 256) {
            int m = bin * BIN_ROWS + (i >> 5);
            if (m < M) out[(size_t)(i & 31) * M + m] = tile[i] + bias[m];
        }
    }
}

// ---------------------------------------------------------------------------
// Fixup: apply coarse-overflow edges (statistically zero) with global
// atomics into out (B, M). Runs AFTER sort_gather.
// ---------------------------------------------------------------------------
__global__ void fixup_kernel(const int* __restrict__ ovCount,
                             const int* __restrict__ ovList,
                             const int* __restrict__ src,
                             const int* __restrict__ dst,
                             const float* __restrict__ vals,
                             const __half* __restrict__ xt,
                             float* __restrict__ out, int M) {
    long long total = (long long)(*ovCount) * 32;
    long long stride = (long long)gridDim.x * blockDim.x;
    for (long long i = (long long)blockIdx.x * blockDim.x + threadIdx.x;
         i < total; i += stride) {
        int k = (int)(i >> 5);
        int b = (int)(i & 31);
        int e = ovList[k];
        atomicAdd(&out[(size_t)b * M + dst[e]],
                  vals[e] * __half2float(xt[(size_t)src[e] * NB + b]));
    }
}

// ---------------------------------------------------------------------------
// yt (M, B) -> out (B, M), + bias (fallback path only).
// ---------------------------------------------------------------------------
__global__ void finalize_kernel(const float* __restrict__ yt,
                                const float* __restrict__ bias,
                                float* __restrict__ out, int M) {
    __shared__ float tile[32][33];
    int m0 = blockIdx.x * 32;
    for (int i = threadIdx.y; i < 32; i += 8) {
        int m = m0 + i;
        tile[i][threadIdx.x] = (m < M) ? yt[(size_t)m * NB + threadIdx.x] : 0.f;
    }
    __syncthreads();
    for (int i = threadIdx.y; i < 32; i += 8) {
        int m = m0 + threadIdx.x;
        if (m < M) out[(size_t)i * M + m] = tile[threadIdx.x][i] + bias[m];
    }
}

// ---------------------------------------------------------------------------
// Fallback: global-atomic scatter (needs only xt + yt).
// ---------------------------------------------------------------------------
__global__ void scatter_kernel(const int* __restrict__ src,
                               const int* __restrict__ dst,
                               const float* __restrict__ vals,
                               const __half* __restrict__ xt,
                               float* __restrict__ yt, int nnz) {
    long long tid = (long long)blockIdx.x * blockDim.x + threadIdx.x;
    int e = (int)(tid >> 5);
    if (e >= nnz) return;
    int b = (int)(tid & 31);
    atomicAdd(&yt[(size_t)dst[e] * NB + b],
              vals[e] * __half2float(xt[(size_t)src[e] * NB + b]));
}

extern "C" void kernel_launch(void* const* d_in, const int* in_sizes, int n_in,
                              void* d_out, int out_size, void* d_ws, size_t ws_size,
                              hipStream_t stream) {
    const float* x       = (const float*)d_in[0];   // (B, N, 1) fp32
    const int*   indices = (const int*)  d_in[1];   // (2, NNZ) int32
    const float* vals    = (const float*)d_in[2];   // (NNZ,) fp32
    const float* bias    = (const float*)d_in[3];   // (M, 1) fp32

    float* out = (float*)d_out;                     // (B, M, 1) fp32

    int nnz = in_sizes[1] / 2;
    int N   = in_sizes[0] / NB;
    int M   = in_sizes[3];

    const int* src = indices;        // row 0
    const int* dst = indices + nnz;  // row 1

    int nbins   = (M + BIN_ROWS - 1) >> BIN_SHIFT;   // 3125 for M=100000
    int ncoarse = (M + (1 << CSHIFT) - 1) >> CSHIFT; // 391 for M=100000

    // primary workspace layout (~77 MB):
    //   xt       N*NB f16               (6.4 MB)
    //   cCursor  NC_MAX i32             | memset-0 region
    //   ovCount  4 i32                  |
    //   fineBase NBINS_MAX i32
    //   fineCnt  NBINS_MAX i32
    //   ovList   nnz i32                (12.8 MB)
    //   cCsr     ncoarse*CAP_C uint2    (28.8 MB)
    //   fineCsr  ncoarse*CAP_C uint2    (28.8 MB)
    __half* xt       = (__half*)d_ws;
    int*    cCursor  = (int*)(xt + (size_t)N * NB);
    int*    ovCount  = cCursor + NC_MAX;
    int*    fineBase = ovCount + 4;
    int*    fineCnt  = fineBase + NBINS_MAX;
    int*    ovList   = fineCnt + NBINS_MAX;
    uint2*  cCsr     = (uint2*)(((uintptr_t)(ovList + nnz) + 15) &
                                ~(uintptr_t)15);
    uint2*  fineCsr  = cCsr + (size_t)ncoarse * CAP_C;

    size_t need = (size_t)((char*)(fineCsr + (size_t)ncoarse * CAP_C) -
                           (char*)d_ws);

    // fallback layout: yt immediately after xt (paths are exclusive)
    float* yt = (float*)(xt + (size_t)N * NB);
    size_t need_fb = (size_t)((char*)(yt + (size_t)M * NB) - (char*)d_ws);

    transpose_x_kernel<<<(N + 31) / 32, dim3(32, 8), 0, stream>>>(x, xt, N);

    if (ws_size >= need && nbins <= NBINS_MAX && ncoarse <= NC_MAX) {
        hipMemsetAsync(cCursor, 0, (NC_MAX + 4) * sizeof(int), stream);
        int fgrid = (nnz + FCHUNK - 1) / FCHUNK;  // 391
        fill_coarse<<<fgrid, FTHREADS, 0, stream>>>(src, dst, vals, cCursor,
                                                    cCsr, ovCount, ovList,
                                                    nnz, ncoarse);
        fill_fine2<<<ncoarse, FTHREADS, 0, stream>>>(cCursor, cCsr, fineCsr,
                                                     fineBase, fineCnt);
        sort_gather<<<nbins, 256, 0, stream>>>(fineBase, fineCnt, fineCsr,
                                               xt, bias, out, M);
        fixup_kernel<<<32, 256, 0, stream>>>(ovCount, ovList, src, dst, vals,
                                             xt, out, M);
    } else if (ws_size >= need_fb) {
        hipMemsetAsync(yt, 0, (size_t)M * NB * sizeof(float), stream);
        long long pairs = (long long)nnz * NB;
        int grid = (int)((pairs + 255) / 256);
        scatter_kernel<<<grid, 256, 0, stream>>>(src, dst, vals, xt, yt, nnz);
        finalize_kernel<<<(M + 31) / 32, dim3(32, 8), 0, stream>>>(yt, bias,
                                                                   out, M);
    }
}

// Round 13
// 205.061 us; speedup vs baseline: 1.0496x; 1.0496x over previous
//
#include <hip/hip_runtime.h>
#include <hip/hip_fp16.h>
#include <stdint.h>

#define NB 32          // batch size B (fixed by problem)
#define CSHIFT 8       // 256 dst rows per coarse region
#define CROWS 256
#define NC_MAX 512     // coarse regions: supports M <= 131072
#define NWAVE 16       // waves per 1024-thread block
#define FCHUNK 8192    // edges per coarse-fill block (= LDS stage size)
#define FTHREADS 1024
#define EPT (FCHUNK / FTHREADS)      // 8
#define CAP_C 9216     // region capacity: mean 8192 + 11 sigma
#define EPT2 (CAP_C / FTHREADS)      // 9
#define SRC_BITS 18    // N < 262144 (problem: N = 100000)
#define SRC_MASK ((1u << SRC_BITS) - 1)
#define GT 512         // row_gather block: 16 half-waves -> 16 consecutive m

// meta layout: bits [25:18] = dst & 255 (row-in-region), bits [17:0] = src

// ---------------------------------------------------------------------------
// x (B, N) f32 -> xt (N, B) f16 transpose. Block 0 also zeroes the cursor /
// ovCount region (replaces a memset dispatch; stream-ordered before fills).
// ---------------------------------------------------------------------------
__global__ void transpose_x_kernel(const float* __restrict__ x,
                                   __half* __restrict__ xt,
                                   int* __restrict__ zeroRegion, int N) {
    __shared__ float tile[32][33];
    if (blockIdx.x == 0) {
        int i = threadIdx.y * 32 + threadIdx.x;
        for (; i < NC_MAX + 4; i += 256) zeroRegion[i] = 0;
    }
    int n0 = blockIdx.x * 32;
    for (int i = threadIdx.y; i < 32; i += 8) {
        int n = n0 + threadIdx.x;
        tile[i][threadIdx.x] = (n < N) ? x[(size_t)i * N + n] : 0.f;
    }
    __syncthreads();
    for (int i = threadIdx.y; i < 32; i += 8) {
        int n = n0 + i;
        if (n < N) xt[(size_t)n * NB + threadIdx.x] =
            __float2half(tile[threadIdx.x][i]);
    }
}

// ---------------------------------------------------------------------------
// Pass 1: LDS-STAGED coarse radix fill. The block counting-sorts its 8192
// edges into an LDS stage ordered by coarse region, then writes the stage
// IN ORDER: a wave's 64 lanes write 64 consecutive entries = few coalesced
// segments (full-line streaming), not 64 scattered partial-line runs.
// This attacks the measured ~1.25 TB/s scattered-write ceiling (r6-r12).
// Region overflow (mean+11sigma, statistically never) -> ovList -> fixup.
// ---------------------------------------------------------------------------
__global__ __launch_bounds__(1024) void fill_coarse(
        const int* __restrict__ src,
        const int* __restrict__ dst,
        const float* __restrict__ vals,
        int* __restrict__ cCursor,   // [NC_MAX], region-relative, 0-init
        uint2* __restrict__ csr,     // [ncoarse*CAP_C]
        int* __restrict__ ovCount,
        int* __restrict__ ovList,
        int nnz) {
    __shared__ uint2 stage[FCHUNK];          // 64 KB, region-sorted entries
    __shared__ unsigned short binOf[FCHUNK]; // 16 KB (0xFFFF = overflow hole)
    __shared__ int lhist[NC_MAX];            // counts -> rank cursors
    __shared__ int lbase[NC_MAX];            // block-local exclusive base
    __shared__ int delta[NC_MAX];            // global claim - lbase
    __shared__ int sscan[NC_MAX];
    int t = threadIdx.x;
    int e0 = blockIdx.x * FCHUNK;
    int chunk = min(FCHUNK, nnz - e0);
    int dcache[EPT], scache[EPT];
    float vcache[EPT];
    for (int i = t; i < NC_MAX; i += FTHREADS) lhist[i] = 0;
    __syncthreads();
#pragma unroll
    for (int q = 0; q < EPT; ++q) {
        int e = e0 + q * FTHREADS + t;
        if (e < nnz) {
            int d = dst[e];
            dcache[q] = d;
            scache[q] = src[e];
            vcache[q] = vals[e];
            atomicAdd(&lhist[d >> CSHIFT], 1);
        } else dcache[q] = -1;
    }
    __syncthreads();
    // exclusive scan over NC_MAX bins (t < 512 participate; all threads sync)
    int v = (t < NC_MAX) ? lhist[t] : 0;
    if (t < NC_MAX) sscan[t] = v;
    __syncthreads();
    for (int off = 1; off < NC_MAX; off <<= 1) {
        int add = (t < NC_MAX && t >= off) ? sscan[t - off] : 0;
        __syncthreads();
        if (t < NC_MAX) sscan[t] += add;
        __syncthreads();
    }
    if (t < NC_MAX) {
        int excl = sscan[t] - v;
        lbase[t] = excl;
        int grel = v ? atomicAdd(&cCursor[t], v) : 0;
        delta[t] = grel - excl;
        lhist[t] = 0;   // reuse as rank cursor
    }
    __syncthreads();
    // scatter into LDS stage (region-sorted); overflow -> hole + ovList
#pragma unroll
    for (int q = 0; q < EPT; ++q) {
        int d = dcache[q];
        if (d >= 0) {
            int bin = d >> CSHIFT;
            int r = atomicAdd(&lhist[bin], 1);
            int pos = lbase[bin] + r;
            if (delta[bin] + pos < CAP_C) {
                stage[pos] = make_uint2(
                    ((uint32_t)(d & (CROWS - 1)) << SRC_BITS) |
                        (uint32_t)scache[q],
                    __float_as_uint(vcache[q]));
                binOf[pos] = (unsigned short)bin;
            } else {
                binOf[pos] = 0xFFFF;
                int op = atomicAdd(ovCount, 1);
                ovList[op] = e0 + q * FTHREADS + t;
            }
        }
    }
    __syncthreads();
    // in-order write: consecutive idx -> consecutive global targets per run
    for (int idx = t; idx < chunk; idx += FTHREADS) {
        unsigned short bo = binOf[idx];
        if (bo != 0xFFFF)
            csr[(size_t)bo * CAP_C + delta[bo] + idx] = stage[idx];
    }
}

// ---------------------------------------------------------------------------
// Pass 2: full ROW sort within each region (one 1024-thr block per region).
// Reads the region's entries once into registers, per-wave 256-row LDS hist,
// 256-wide scan, ranked scatter -> row-sorted fineCsr + rowBase/rowCnt.
// Exact packing: no caps, no overflow. Output feeds an LDS-free gather.
// ---------------------------------------------------------------------------
__global__ __launch_bounds__(1024) void fill_fine2(
        const int* __restrict__ cCursor,
        const uint2* __restrict__ cCsr,
        uint2* __restrict__ fineCsr,
        int* __restrict__ rowBase,
        int* __restrict__ rowCnt, int M) {
    __shared__ int whist[NWAVE][CROWS];  // 16 KB: counts -> cursors
    __shared__ int fbase[CROWS];
    __shared__ int sscan[CROWS];
    int c = blockIdx.x;
    int n = min(cCursor[c], CAP_C);
    int t = threadIdx.x;
    int w = t >> 6;                      // wave id 0..15
    uint2 ec[EPT2];
    for (int i = t; i < NWAVE * CROWS; i += FTHREADS) (&whist[0][0])[i] = 0;
    __syncthreads();
    const uint2* reg = cCsr + (size_t)c * CAP_C;
#pragma unroll
    for (int q = 0; q < EPT2; ++q) {
        int j = q * FTHREADS + t;
        if (j < n) {
            uint2 e = reg[j];
            ec[q] = e;
            atomicAdd(&whist[w][(e.x >> SRC_BITS) & (CROWS - 1)], 1);
        }
    }
    __syncthreads();
    // per-row totals + exclusive scan over 256 rows (t < 256 participate)
    int tot = 0;
    if (t < CROWS) {
#pragma unroll
        for (int w2 = 0; w2 < NWAVE; ++w2) tot += whist[w2][t];
        sscan[t] = tot;
    }
    __syncthreads();
    for (int off = 1; off < CROWS; off <<= 1) {
        int add = (t < CROWS && t >= off) ? sscan[t - off] : 0;
        __syncthreads();
        if (t < CROWS) sscan[t] += add;
        __syncthreads();
    }
    if (t < CROWS) {
        int excl = sscan[t] - tot;
        fbase[t] = excl;
        int m = c * CROWS + t;
        if (m < M) {
            rowBase[m] = c * CAP_C + excl;   // absolute index into fineCsr
            rowCnt[m]  = tot;
        }
        int run = excl;
#pragma unroll
        for (int w2 = 0; w2 < NWAVE; ++w2) {
            int cn = whist[w2][t];
            whist[w2][t] = run;              // cursor for (wave, row)
            run += cn;
        }
    }
    __syncthreads();
#pragma unroll
    for (int q = 0; q < EPT2; ++q) {
        int j = q * FTHREADS + t;
        if (j < n) {
            uint2 e = ec[q];
            int p = atomicAdd(&whist[w][(e.x >> SRC_BITS) & (CROWS - 1)], 1);
            fineCsr[(size_t)c * CAP_C + p] = e;
        }
    }
}

// ---------------------------------------------------------------------------
// LDS-free row gather: one half-wave (32 lanes = 32 batch cols) per output
// row m, walking its contiguous row-sorted entry list. Pure register
// accumulation, 8-deep load pipeline, NO atomics, NO LDS -> max occupancy.
// 512-thr blocks cover 16 consecutive m: each lane's 16 out-stores form one
// full 64B line (L2-merged within the block's XCD). Bias fused.
// Correct for arbitrary skew (a hot row is just a longer loop).
// ---------------------------------------------------------------------------
__global__ __launch_bounds__(GT) void row_gather(
        const int* __restrict__ rowBase,
        const int* __restrict__ rowCnt,
        const uint2* __restrict__ csr,
        const __half* __restrict__ xt,
        const float* __restrict__ bias,
        float* __restrict__ out, int M) {
    int g = threadIdx.x >> 5;            // half-wave id 0..15
    int b = threadIdx.x & 31;            // batch lane
    int m = blockIdx.x * (GT / 32) + g;
    if (m >= M) return;
    int j   = rowBase[m];
    int end = j + rowCnt[m];
    float acc0 = 0.f, acc1 = 0.f;
    for (; j + 8 <= end; j += 8) {
        uint2 e0 = csr[j + 0];
        uint2 e1 = csr[j + 1];
        uint2 e2 = csr[j + 2];
        uint2 e3 = csr[j + 3];
        uint2 e4 = csr[j + 4];
        uint2 e5 = csr[j + 5];
        uint2 e6 = csr[j + 6];
        uint2 e7 = csr[j + 7];
        float x0 = __half2float(xt[(size_t)(e0.x & SRC_MASK) * NB + b]);
        float x1 = __half2float(xt[(size_t)(e1.x & SRC_MASK) * NB + b]);
        float x2 = __half2float(xt[(size_t)(e2.x & SRC_MASK) * NB + b]);
        float x3 = __half2float(xt[(size_t)(e3.x & SRC_MASK) * NB + b]);
        float x4 = __half2float(xt[(size_t)(e4.x & SRC_MASK) * NB + b]);
        float x5 = __half2float(xt[(size_t)(e5.x & SRC_MASK) * NB + b]);
        float x6 = __half2float(xt[(size_t)(e6.x & SRC_MASK) * NB + b]);
        float x7 = __half2float(xt[(size_t)(e7.x & SRC_MASK) * NB + b]);
        acc0 = fmaf(__uint_as_float(e0.y), x0, acc0);
        acc1 = fmaf(__uint_as_float(e1.y), x1, acc1);
        acc0 = fmaf(__uint_as_float(e2.y), x2, acc0);
        acc1 = fmaf(__uint_as_float(e3.y), x3, acc1);
        acc0 = fmaf(__uint_as_float(e4.y), x4, acc0);
        acc1 = fmaf(__uint_as_float(e5.y), x5, acc1);
        acc0 = fmaf(__uint_as_float(e6.y), x6, acc0);
        acc1 = fmaf(__uint_as_float(e7.y), x7, acc1);
    }
    for (; j < end; ++j) {
        uint2 e = csr[j];
        acc0 = fmaf(__uint_as_float(e.y),
                    __half2float(xt[(size_t)(e.x & SRC_MASK) * NB + b]),
                    acc0);
    }
    out[(size_t)b * M + m] = acc0 + acc1 + bias[m];
}

// ---------------------------------------------------------------------------
// Fixup: apply coarse-overflow edges (statistically zero) with global
// atomics into out (B, M). Runs AFTER row_gather.
// ---------------------------------------------------------------------------
__global__ void fixup_kernel(const int* __restrict__ ovCount,
                             const int* __restrict__ ovList,
                             const int* __restrict__ src,
                             const int* __restrict__ dst,
                             const float* __restrict__ vals,
                             const __half* __restrict__ xt,
                             float* __restrict__ out, int M) {
    long long total = (long long)(*ovCount) * 32;
    long long stride = (long long)gridDim.x * blockDim.x;
    for (long long i = (long long)blockIdx.x * blockDim.x + threadIdx.x;
         i < total; i += stride) {
        int k = (int)(i >> 5);
        int b = (int)(i & 31);
        int e = ovList[k];
        atomicAdd(&out[(size_t)b * M + dst[e]],
                  vals[e] * __half2float(xt[(size_t)src[e] * NB + b]));
    }
}

// ---------------------------------------------------------------------------
// yt (M, B) -> out (B, M), + bias (fallback path only).
// ---------------------------------------------------------------------------
__global__ void finalize_kernel(const float* __restrict__ yt,
                                const float* __restrict__ bias,
                                float* __restrict__ out, int M) {
    __shared__ float tile[32][33];
    int m0 = blockIdx.x * 32;
    for (int i = threadIdx.y; i < 32; i += 8) {
        int m = m0 + i;
        tile[i][threadIdx.x] = (m < M) ? yt[(size_t)m * NB + threadIdx.x] : 0.f;
    }
    __syncthreads();
    for (int i = threadIdx.y; i < 32; i += 8) {
        int m = m0 + threadIdx.x;
        if (m < M) out[(size_t)i * M + m] = tile[threadIdx.x][i] + bias[m];
    }
}

// ---------------------------------------------------------------------------
// Fallback: global-atomic scatter (needs only xt + yt).
// ---------------------------------------------------------------------------
__global__ void scatter_kernel(const int* __restrict__ src,
                               const int* __restrict__ dst,
                               const float* __restrict__ vals,
                               const __half* __restrict__ xt,
                               float* __restrict__ yt, int nnz) {
    long long tid = (long long)blockIdx.x * blockDim.x + threadIdx.x;
    int e = (int)(tid >> 5);
    if (e >= nnz) return;
    int b = (int)(tid & 31);
    atomicAdd(&yt[(size_t)dst[e] * NB + b],
              vals[e] * __half2float(xt[(size_t)src[e] * NB + b]));
}

extern "C" void kernel_launch(void* const* d_in, const int* in_sizes, int n_in,
                              void* d_out, int out_size, void* d_ws, size_t ws_size,
                              hipStream_t stream) {
    const float* x       = (const float*)d_in[0];   // (B, N, 1) fp32
    const int*   indices = (const int*)  d_in[1];   // (2, NNZ) int32
    const float* vals    = (const float*)d_in[2];   // (NNZ,) fp32
    const float* bias    = (const float*)d_in[3];   // (M, 1) fp32

    float* out = (float*)d_out;                     // (B, M, 1) fp32

    int nnz = in_sizes[1] / 2;
    int N   = in_sizes[0] / NB;
    int M   = in_sizes[3];

    const int* src = indices;        // row 0
    const int* dst = indices + nnz;  // row 1

    int ncoarse = (M + CROWS - 1) >> CSHIFT;   // 391 for M=100000

    // primary workspace layout (~78 MB):
    //   xt       N*NB f16                (6.4 MB)
    //   cCursor  NC_MAX i32              | zeroed by transpose block 0
    //   ovCount  4 i32                   |
    //   rowBase  M i32                   (0.4 MB)
    //   rowCnt   M i32                   (0.4 MB)
    //   ovList   nnz i32                 (12.8 MB)
    //   cCsr     ncoarse*CAP_C uint2     (28.8 MB)
    //   fineCsr  ncoarse*CAP_C uint2     (28.8 MB)
    __half* xt      = (__half*)d_ws;
    int*    cCursor = (int*)(xt + (size_t)N * NB);
    int*    ovCount = cCursor + NC_MAX;
    int*    rowBase = ovCount + 4;
    int*    rowCnt  = rowBase + M;
    int*    ovList  = rowCnt + M;
    uint2*  cCsr    = (uint2*)(((uintptr_t)(ovList + nnz) + 15) &
                               ~(uintptr_t)15);
    uint2*  fineCsr = cCsr + (size_t)ncoarse * CAP_C;

    size_t need = (size_t)((char*)(fineCsr + (size_t)ncoarse * CAP_C) -
                           (char*)d_ws);

    // fallback layout: yt immediately after xt (paths are exclusive)
    float* yt = (float*)(xt + (size_t)N * NB);
    size_t need_fb = (size_t)((char*)(yt + (size_t)M * NB) - (char*)d_ws);

    if (ws_size >= need && ncoarse <= NC_MAX) {
        transpose_x_kernel<<<(N + 31) / 32, dim3(32, 8), 0, stream>>>(
            x, xt, cCursor, N);
        int fgrid = (nnz + FCHUNK - 1) / FCHUNK;  // 391
        fill_coarse<<<fgrid, FTHREADS, 0, stream>>>(src, dst, vals, cCursor,
                                                    cCsr, ovCount, ovList,
                                                    nnz);
        fill_fine2<<<ncoarse, FTHREADS, 0, stream>>>(cCursor, cCsr, fineCsr,
                                                     rowBase, rowCnt, M);
        row_gather<<<(M + GT / 32 - 1) / (GT / 32), GT, 0, stream>>>(
            rowBase, rowCnt, fineCsr, xt, bias, out, M);
        fixup_kernel<<<32, 256, 0, stream>>>(ovCount, ovList, src, dst, vals,
                                             xt, out, M);
    } else if (ws_size >= need_fb) {
        transpose_x_kernel<<<(N + 31) / 32, dim3(32, 8), 0, stream>>>(
            x, xt, cCursor, N);  // zeroRegion overlaps yt start; harmless
        hipMemsetAsync(yt, 0, (size_t)M * NB * sizeof(float), stream);
        long long pairs = (long long)nnz * NB;
        int grid = (int)((pairs + 255) / 256);
        scatter_kernel<<<grid, 256, 0, stream>>>(src, dst, vals, xt, yt, nnz);
        finalize_kernel<<<(M + 31) / 32, dim3(32, 8), 0, stream>>>(yt, bias,
                                                                   out, M);
    }
}

// Round 14
// 194.275 us; speedup vs baseline: 1.1079x; 1.0555x over previous
//
#include <hip/hip_runtime.h>
#include <hip/hip_fp16.h>
#include <stdint.h>

#define NB 32          // batch size B (fixed by problem)
#define CSHIFT 7       // 128 dst rows per region
#define CROWS 128
#define NC_MAX 1024    // regions: supports M <= 131072
#define FCHUNK 8192    // edges per fill block (= LDS stage size)
#define FTHREADS 1024
#define EPT (FCHUNK / FTHREADS)      // 8
#define CAP_C 4608     // region capacity: mean 4092 + 8 sigma (overflow->fixup)
#define GTHREADS 512   // gather block: 8 waves, 16 half-waves
#define NGW 8          // waves per gather block
#define GEPT ((CAP_C + GTHREADS - 1) / GTHREADS)  // 9 entries/thread
#define SRC_BITS 18    // N < 262144 (problem: N = 100000)
#define SRC_MASK ((1u << SRC_BITS) - 1)

// meta layout: bits [24:18] = dst & 127 (row-in-region), bits [17:0] = src

// ---------------------------------------------------------------------------
// x (B, N) f32 -> xt (N, B) f16 transpose. Block 0 zeroes cursors+ovCount.
// ---------------------------------------------------------------------------
__global__ void transpose_x_kernel(const float* __restrict__ x,
                                   __half* __restrict__ xt,
                                   int* __restrict__ zeroRegion, int N) {
    __shared__ float tile[32][33];
    if (blockIdx.x == 0) {
        int i = threadIdx.y * 32 + threadIdx.x;
        for (; i < NC_MAX + 4; i += 256) zeroRegion[i] = 0;
    }
    int n0 = blockIdx.x * 32;
    for (int i = threadIdx.y; i < 32; i += 8) {
        int n = n0 + threadIdx.x;
        tile[i][threadIdx.x] = (n < N) ? x[(size_t)i * N + n] : 0.f;
    }
    __syncthreads();
    for (int i = threadIdx.y; i < 32; i += 8) {
        int n = n0 + i;
        if (n < N) xt[(size_t)n * NB + threadIdx.x] =
            __float2half(tile[threadIdx.x][i]);
    }
}

// ---------------------------------------------------------------------------
// LDS-staged region fill (r13-proven structure, 128-row regions):
// block counting-sorts its 8192 edges into a 64KB LDS stage ordered by
// region, then writes the stage IN ORDER -> coalesced segments, not 64
// scattered runs per wave. Region overflow (mean+8sigma, statistically
// never; correctness via fixup) -> ovList.
// ---------------------------------------------------------------------------
__global__ __launch_bounds__(1024) void fill_coarse(
        const int* __restrict__ src,
        const int* __restrict__ dst,
        const float* __restrict__ vals,
        int* __restrict__ cCursor,   // [NC_MAX], region-relative, 0-init
        uint2* __restrict__ csr,     // [ncoarse*CAP_C]
        int* __restrict__ ovCount,
        int* __restrict__ ovList,
        int nnz) {
    __shared__ uint2 stage[FCHUNK];          // 64 KB, region-sorted entries
    __shared__ unsigned short binOf[FCHUNK]; // 16 KB (0xFFFF = overflow hole)
    __shared__ int lhist[NC_MAX];            // counts -> rank cursors (4 KB)
    __shared__ int lbase[NC_MAX];            // block-local exclusive base
    __shared__ int delta[NC_MAX];            // global claim - lbase
    int t = threadIdx.x;
    int e0 = blockIdx.x * FCHUNK;
    int chunk = min(FCHUNK, nnz - e0);
    int dcache[EPT], scache[EPT];
    float vcache[EPT];
    lhist[t] = 0;
    __syncthreads();
#pragma unroll
    for (int q = 0; q < EPT; ++q) {
        int e = e0 + q * FTHREADS + t;
        if (e < nnz) {
            int d = dst[e];
            dcache[q] = d;
            scache[q] = src[e];
            vcache[q] = vals[e];
            atomicAdd(&lhist[d >> CSHIFT], 1);
        } else dcache[q] = -1;
    }
    __syncthreads();
    // exclusive scan over 1024 bins (1 per thread, Hillis-Steele in lbase)
    int v = lhist[t];
    lbase[t] = v;
    __syncthreads();
    for (int off = 1; off < NC_MAX; off <<= 1) {
        int add = (t >= off) ? lbase[t - off] : 0;
        __syncthreads();
        lbase[t] += add;
        __syncthreads();
    }
    {
        int excl = lbase[t] - v;
        lbase[t] = excl;
        int grel = v ? atomicAdd(&cCursor[t], v) : 0;
        delta[t] = grel - excl;
        lhist[t] = 0;   // reuse as rank cursor
    }
    __syncthreads();
    // scatter into LDS stage (region-sorted); overflow -> hole + ovList
#pragma unroll
    for (int q = 0; q < EPT; ++q) {
        int d = dcache[q];
        if (d >= 0) {
            int bin = d >> CSHIFT;
            int r = atomicAdd(&lhist[bin], 1);
            int pos = lbase[bin] + r;
            if (delta[bin] + pos < CAP_C) {
                stage[pos] = make_uint2(
                    ((uint32_t)(d & (CROWS - 1)) << SRC_BITS) |
                        (uint32_t)scache[q],
                    __float_as_uint(vcache[q]));
                binOf[pos] = (unsigned short)bin;
            } else {
                binOf[pos] = 0xFFFF;
                int op = atomicAdd(ovCount, 1);
                ovList[op] = e0 + q * FTHREADS + t;
            }
        }
    }
    __syncthreads();
    // in-order write: consecutive idx -> consecutive global targets per run
    for (int idx = t; idx < chunk; idx += FTHREADS) {
        unsigned short bo = binOf[idx];
        if (bo != 0xFFFF)
            csr[(size_t)bo * CAP_C + delta[bo] + idx] = stage[idx];
    }
}

// ---------------------------------------------------------------------------
// Fused region sort + gather + bias + output-transpose: one 512-thr block
// per 128-row region. The row sort lives ENTIRELY in LDS (never touches
// HBM): coalesced register read -> per-wave 128-row hist -> scan -> ranked
// LDS scatter -> per-row gather (8-deep fp16 xt pipeline, fp32 acc, no
// atomics) -> direct out write. Replaces fill_fine2 + fineCsr (58 MB of
// HBM traffic) + row_gather's broadcast global entry reads.
// LDS ~41.5 KB -> 3 blocks/CU = 24 waves/CU; 782 blocks ~= 3.05/CU.
// ---------------------------------------------------------------------------
__global__ __launch_bounds__(GTHREADS) void region_sort_gather(
        const int* __restrict__ cCursor,
        const uint2* __restrict__ cCsr,
        const __half* __restrict__ xt,
        const float* __restrict__ bias,
        float* __restrict__ out, int M) {
    __shared__ uint2 sorted[CAP_C];       // 36 KB
    __shared__ int whist[NGW][CROWS];     // 4 KB: counts -> cursors
    __shared__ int rowOff[CROWS];         // exclusive row base
    __shared__ int rowCnt[CROWS];
    int c = blockIdx.x;
    int n = min(cCursor[c], CAP_C);
    int t = threadIdx.x;
    int w = t >> 6;                       // wave id 0..7
    uint2 ec[GEPT];
    for (int i = t; i < NGW * CROWS; i += GTHREADS) (&whist[0][0])[i] = 0;
    __syncthreads();
    const uint2* reg = cCsr + (size_t)c * CAP_C;
#pragma unroll
    for (int q = 0; q < GEPT; ++q) {
        int j = q * GTHREADS + t;
        if (j < n) {
            uint2 e = reg[j];
            ec[q] = e;
            atomicAdd(&whist[w][(e.x >> SRC_BITS) & (CROWS - 1)], 1);
        }
    }
    __syncthreads();
    // per-row totals + exclusive scan over 128 rows (t < 128 participate)
    int tot = 0;
    if (t < CROWS) {
#pragma unroll
        for (int w2 = 0; w2 < NGW; ++w2) tot += whist[w2][t];
        rowCnt[t] = tot;
        rowOff[t] = tot;
    }
    __syncthreads();
    for (int off = 1; off < CROWS; off <<= 1) {
        int add = (t < CROWS && t >= off) ? rowOff[t - off] : 0;
        __syncthreads();
        if (t < CROWS) rowOff[t] += add;
        __syncthreads();
    }
    if (t < CROWS) {
        int excl = rowOff[t] - rowCnt[t];
        rowOff[t] = excl;
        int run = excl;
#pragma unroll
        for (int w2 = 0; w2 < NGW; ++w2) {
            int cn = whist[w2][t];
            whist[w2][t] = run;           // cursor for (wave, row)
            run += cn;
        }
    }
    __syncthreads();
#pragma unroll
    for (int q = 0; q < GEPT; ++q) {
        int j = q * GTHREADS + t;
        if (j < n) {
            uint2 e = ec[q];
            int p = atomicAdd(&whist[w][(e.x >> SRC_BITS) & (CROWS - 1)], 1);
            sorted[p] = e;
        }
    }
    __syncthreads();
    // gather: 16 half-waves x 8 rows each; entries from LDS, xt from global
    int g = t >> 5;                       // half-wave id 0..15
    int b = t & 31;                       // batch lane
    for (int r = g; r < CROWS; r += GTHREADS / 32) {
        int m = c * CROWS + r;
        if (m >= M) break;
        int jj   = rowOff[r];
        int jend = jj + rowCnt[r];
        float acc0 = 0.f, acc1 = 0.f;
        for (; jj + 8 <= jend; jj += 8) {
            uint2 e0 = sorted[jj + 0];
            uint2 e1 = sorted[jj + 1];
            uint2 e2 = sorted[jj + 2];
            uint2 e3 = sorted[jj + 3];
            uint2 e4 = sorted[jj + 4];
            uint2 e5 = sorted[jj + 5];
            uint2 e6 = sorted[jj + 6];
            uint2 e7 = sorted[jj + 7];
            float x0 = __half2float(xt[(size_t)(e0.x & SRC_MASK) * NB + b]);
            float x1 = __half2float(xt[(size_t)(e1.x & SRC_MASK) * NB + b]);
            float x2 = __half2float(xt[(size_t)(e2.x & SRC_MASK) * NB + b]);
            float x3 = __half2float(xt[(size_t)(e3.x & SRC_MASK) * NB + b]);
            float x4 = __half2float(xt[(size_t)(e4.x & SRC_MASK) * NB + b]);
            float x5 = __half2float(xt[(size_t)(e5.x & SRC_MASK) * NB + b]);
            float x6 = __half2float(xt[(size_t)(e6.x & SRC_MASK) * NB + b]);
            float x7 = __half2float(xt[(size_t)(e7.x & SRC_MASK) * NB + b]);
            acc0 = fmaf(__uint_as_float(e0.y), x0, acc0);
            acc1 = fmaf(__uint_as_float(e1.y), x1, acc1);
            acc0 = fmaf(__uint_as_float(e2.y), x2, acc0);
            acc1 = fmaf(__uint_as_float(e3.y), x3, acc1);
            acc0 = fmaf(__uint_as_float(e4.y), x4, acc0);
            acc1 = fmaf(__uint_as_float(e5.y), x5, acc1);
            acc0 = fmaf(__uint_as_float(e6.y), x6, acc0);
            acc1 = fmaf(__uint_as_float(e7.y), x7, acc1);
        }
        for (; jj < jend; ++jj) {
            uint2 e = sorted[jj];
            acc0 = fmaf(__uint_as_float(e.y),
                        __half2float(xt[(size_t)(e.x & SRC_MASK) * NB + b]),
                        acc0);
        }
        out[(size_t)b * M + m] = acc0 + acc1 + bias[m];
    }
}

// ---------------------------------------------------------------------------
// Fixup: apply overflow edges (statistically zero) with global atomics
// into out (B, M). Runs AFTER region_sort_gather.
// ---------------------------------------------------------------------------
__global__ void fixup_kernel(const int* __restrict__ ovCount,
                             const int* __restrict__ ovList,
                             const int* __restrict__ src,
                             const int* __restrict__ dst,
                             const float* __restrict__ vals,
                             const __half* __restrict__ xt,
                             float* __restrict__ out, int M) {
    long long total = (long long)(*ovCount) * 32;
    long long stride = (long long)gridDim.x * blockDim.x;
    for (long long i = (long long)blockIdx.x * blockDim.x + threadIdx.x;
         i < total; i += stride) {
        int k = (int)(i >> 5);
        int b = (int)(i & 31);
        int e = ovList[k];
        atomicAdd(&out[(size_t)b * M + dst[e]],
                  vals[e] * __half2float(xt[(size_t)src[e] * NB + b]));
    }
}

// ---------------------------------------------------------------------------
// yt (M, B) -> out (B, M), + bias (fallback path only).
// ---------------------------------------------------------------------------
__global__ void finalize_kernel(const float* __restrict__ yt,
                                const float* __restrict__ bias,
                                float* __restrict__ out, int M) {
    __shared__ float tile[32][33];
    int m0 = blockIdx.x * 32;
    for (int i = threadIdx.y; i < 32; i += 8) {
        int m = m0 + i;
        tile[i][threadIdx.x] = (m < M) ? yt[(size_t)m * NB + threadIdx.x] : 0.f;
    }
    __syncthreads();
    for (int i = threadIdx.y; i < 32; i += 8) {
        int m = m0 + threadIdx.x;
        if (m < M) out[(size_t)i * M + m] = tile[threadIdx.x][i] + bias[m];
    }
}

// ---------------------------------------------------------------------------
// Fallback: global-atomic scatter (needs only xt + yt).
// ---------------------------------------------------------------------------
__global__ void scatter_kernel(const int* __restrict__ src,
                               const int* __restrict__ dst,
                               const float* __restrict__ vals,
                               const __half* __restrict__ xt,
                               float* __restrict__ yt, int nnz) {
    long long tid = (long long)blockIdx.x * blockDim.x + threadIdx.x;
    int e = (int)(tid >> 5);
    if (e >= nnz) return;
    int b = (int)(tid & 31);
    atomicAdd(&yt[(size_t)dst[e] * NB + b],
              vals[e] * __half2float(xt[(size_t)src[e] * NB + b]));
}

extern "C" void kernel_launch(void* const* d_in, const int* in_sizes, int n_in,
                              void* d_out, int out_size, void* d_ws, size_t ws_size,
                              hipStream_t stream) {
    const float* x       = (const float*)d_in[0];   // (B, N, 1) fp32
    const int*   indices = (const int*)  d_in[1];   // (2, NNZ) int32
    const float* vals    = (const float*)d_in[2];   // (NNZ,) fp32
    const float* bias    = (const float*)d_in[3];   // (M, 1) fp32

    float* out = (float*)d_out;                     // (B, M, 1) fp32

    int nnz = in_sizes[1] / 2;
    int N   = in_sizes[0] / NB;
    int M   = in_sizes[3];

    const int* src = indices;        // row 0
    const int* dst = indices + nnz;  // row 1

    int ncoarse = (M + CROWS - 1) >> CSHIFT;   // 782 for M=100000

    // primary workspace layout (~48 MB):
    //   xt       N*NB f16                (6.4 MB)
    //   cCursor  NC_MAX i32              | zeroed by transpose block 0
    //   ovCount  4 i32                   |
    //   ovList   nnz i32                 (12.8 MB)
    //   cCsr     ncoarse*CAP_C uint2     (28.8 MB)
    __half* xt      = (__half*)d_ws;
    int*    cCursor = (int*)(xt + (size_t)N * NB);
    int*    ovCount = cCursor + NC_MAX;
    int*    ovList  = ovCount + 4;
    uint2*  cCsr    = (uint2*)(((uintptr_t)(ovList + nnz) + 15) &
                               ~(uintptr_t)15);

    size_t need = (size_t)((char*)(cCsr + (size_t)ncoarse * CAP_C) -
                           (char*)d_ws);

    // fallback layout: yt immediately after xt (paths are exclusive)
    float* yt = (float*)(xt + (size_t)N * NB);
    size_t need_fb = (size_t)((char*)(yt + (size_t)M * NB) - (char*)d_ws);

    if (ws_size >= need && ncoarse <= NC_MAX) {
        transpose_x_kernel<<<(N + 31) / 32, dim3(32, 8), 0, stream>>>(
            x, xt, cCursor, N);
        int fgrid = (nnz + FCHUNK - 1) / FCHUNK;  // 391
        fill_coarse<<<fgrid, FTHREADS, 0, stream>>>(src, dst, vals, cCursor,
                                                    cCsr, ovCount, ovList,
                                                    nnz);
        region_sort_gather<<<ncoarse, GTHREADS, 0, stream>>>(cCursor, cCsr,
                                                             xt, bias, out, M);
        fixup_kernel<<<32, 256, 0, stream>>>(ovCount, ovList, src, dst, vals,
                                             xt, out, M);
    } else if (ws_size >= need_fb) {
        transpose_x_kernel<<<(N + 31) / 32, dim3(32, 8), 0, stream>>>(
            x, xt, cCursor, N);  // zeroRegion overlaps yt start; harmless
        hipMemsetAsync(yt, 0, (size_t)M * NB * sizeof(float), stream);
        long long pairs = (long long)nnz * NB;
        int grid = (int)((pairs + 255) / 256);
        scatter_kernel<<<grid, 256, 0, stream>>>(src, dst, vals, xt, yt, nnz);
        finalize_kernel<<<(M + 31) / 32, dim3(32, 8), 0, stream>>>(yt, bias,
                                                                   out, M);
    }
}

// Round 15
// 176.754 us; speedup vs baseline: 1.2177x; 1.0991x over previous
//
#include <hip/hip_runtime.h>
#include <hip/hip_fp16.h>
#include <stdint.h>

#define NB 32          // batch size B (fixed by problem)
#define CSHIFT 7       // 128 dst rows per region
#define CROWS 128
#define NC_MAX 1024    // regions: supports M <= 131072
#define FCHUNK 8192    // edges per fill block
#define FTHREADS 512   // fill threads (8 waves; LDS 52KB -> ~3 blocks/CU)
#define EPT (FCHUNK / FTHREADS)      // 16
#define HSTAGE 4096    // LDS stage half-size (2 store rounds per chunk)
#define CAP_C 4608     // region capacity: mean 4096 + 8 sigma (overflow->fixup)
#define GTHREADS 512   // gather block: 8 waves, 16 half-waves
#define NGW 8          // waves per gather block
#define GEPT ((CAP_C + GTHREADS - 1) / GTHREADS)  // 9 entries/thread
#define HCAP 2816      // sorted-half capacity: mean 2048 + 17 sigma
#define SRC_BITS 18    // N < 262144 (problem: N = 100000)
#define SRC_MASK ((1u << SRC_BITS) - 1)

// meta layout: bits [24:18] = dst & 127 (row-in-region), bits [17:0] = src

// ---------------------------------------------------------------------------
// x (B, N) f32 -> xt (N, B) f16 transpose. Block 0 zeroes cursors+ovCount.
// ---------------------------------------------------------------------------
__global__ void transpose_x_kernel(const float* __restrict__ x,
                                   __half* __restrict__ xt,
                                   int* __restrict__ zeroRegion, int N) {
    __shared__ float tile[32][33];
    if (blockIdx.x == 0) {
        int i = threadIdx.y * 32 + threadIdx.x;
        for (; i < NC_MAX + 4; i += 256) zeroRegion[i] = 0;
    }
    int n0 = blockIdx.x * 32;
    for (int i = threadIdx.y; i < 32; i += 8) {
        int n = n0 + threadIdx.x;
        tile[i][threadIdx.x] = (n < N) ? x[(size_t)i * N + n] : 0.f;
    }
    __syncthreads();
    for (int i = threadIdx.y; i < 32; i += 8) {
        int n = n0 + i;
        if (n < N) xt[(size_t)n * NB + threadIdx.x] =
            __float2half(tile[threadIdx.x][i]);
    }
}

// ---------------------------------------------------------------------------
// LDS-staged region fill, SPLIT STAGE (52 KB LDS -> ~3 blocks/CU vs r14's
// 92 KB -> 1): positions computed once; two store rounds each scatter the
// pos range [h*4096,(h+1)*4096) into a 4096-entry stage, then write the
// stage IN ORDER (coalesced ~84B runs). Region overflow (mean+8sigma,
// statistically never; correctness via fixup) -> ovList.
// ---------------------------------------------------------------------------
__global__ __launch_bounds__(FTHREADS) void fill_coarse(
        const int* __restrict__ src,
        const int* __restrict__ dst,
        const float* __restrict__ vals,
        int* __restrict__ cCursor,   // [NC_MAX], region-relative, 0-init
        uint2* __restrict__ csr,     // [ncoarse*CAP_C]
        int* __restrict__ ovCount,
        int* __restrict__ ovList,
        int nnz) {
    __shared__ uint2 stage[HSTAGE];          // 32 KB
    __shared__ unsigned short sbin[HSTAGE];  // 8 KB (0xFFFF = hole)
    __shared__ int lhist[NC_MAX];            // 4 KB: counts -> rank cursors
    __shared__ int lbase[NC_MAX];            // 4 KB: block-local excl base
    __shared__ int delta[NC_MAX];            // 4 KB: global claim - lbase
    int t = threadIdx.x;
    int e0 = blockIdx.x * FCHUNK;
    int chunk = min(FCHUNK, nnz - e0);
    int      bcache[EPT];   // region bin; -1 = oob, -2 = overflow
    uint32_t mcache[EPT];   // packed meta
    uint32_t vcache[EPT];   // val bits
    int      pcache[EPT];   // chunk-wide position
    for (int i = t; i < NC_MAX; i += FTHREADS) lhist[i] = 0;
    __syncthreads();
#pragma unroll
    for (int q = 0; q < EPT; ++q) {
        int e = e0 + q * FTHREADS + t;
        if (e < nnz) {
            int d = dst[e];
            int bin = d >> CSHIFT;
            bcache[q] = bin;
            mcache[q] = ((uint32_t)(d & (CROWS - 1)) << SRC_BITS) |
                        (uint32_t)src[e];
            vcache[q] = __float_as_uint(vals[e]);
            atomicAdd(&lhist[bin], 1);
        } else bcache[q] = -1;
    }
    __syncthreads();
    // exclusive scan over 1024 bins: 2 per thread + 512-wide Hillis-Steele
    int s0 = lhist[2 * t];
    int s1 = lhist[2 * t + 1];
    int tsum = s0 + s1;
    lbase[t] = tsum;   // reuse low half as scan workspace
    __syncthreads();
    for (int off = 1; off < FTHREADS; off <<= 1) {
        int add = (t >= off) ? lbase[t - off] : 0;
        __syncthreads();
        lbase[t] += add;
        __syncthreads();
    }
    int texcl = lbase[t] - tsum;
    __syncthreads();           // scan workspace reads done
    lbase[2 * t]     = texcl;
    lbase[2 * t + 1] = texcl + s0;
    {
        int g0 = s0 ? atomicAdd(&cCursor[2 * t], s0) : 0;
        int g1 = s1 ? atomicAdd(&cCursor[2 * t + 1], s1) : 0;
        delta[2 * t]     = g0 - texcl;
        delta[2 * t + 1] = g1 - (texcl + s0);
        lhist[2 * t]     = 0;   // reuse as rank cursors
        lhist[2 * t + 1] = 0;
    }
    __syncthreads();
    // chunk-wide position per entry (rank claim); overflow -> ovList
#pragma unroll
    for (int q = 0; q < EPT; ++q) {
        int bin = bcache[q];
        if (bin >= 0) {
            int r = atomicAdd(&lhist[bin], 1);
            int pos = lbase[bin] + r;
            pcache[q] = pos;
            if (delta[bin] + pos >= CAP_C) {
                bcache[q] = -2;
                int op = atomicAdd(ovCount, 1);
                ovList[op] = e0 + q * FTHREADS + t;
            }
        }
    }
    __syncthreads();
    // two store rounds: scatter pos range into stage, write in order
    for (int h = 0; h < FCHUNK / HSTAGE; ++h) {
        int lo = h * HSTAGE;
#pragma unroll
        for (int q = 0; q < EPT; ++q) {
            if (bcache[q] != -1) {
                int p = pcache[q];
                if (p >= lo && p < lo + HSTAGE) {
                    int s = p - lo;
                    if (bcache[q] >= 0) {
                        stage[s] = make_uint2(mcache[q], vcache[q]);
                        sbin[s] = (unsigned short)bcache[q];
                    } else sbin[s] = 0xFFFF;
                }
            }
        }
        __syncthreads();
        int lim = min(HSTAGE, chunk - lo);
        for (int idx = t; idx < lim; idx += FTHREADS) {
            unsigned short bo = sbin[idx];
            if (bo != 0xFFFF)
                csr[(size_t)bo * CAP_C + delta[bo] + lo + idx] = stage[idx];
        }
        __syncthreads();
    }
}

// ---------------------------------------------------------------------------
// Fused region sort + gather + bias + output-transpose, HALF-ROW ROUNDS:
// hist+scan over all 128 rows once (absolute cursors), then 2 rounds each
// {scatter 64 rows into a 2816-entry LDS buffer, gather those rows}. LDS
// 42 -> ~28 KB => 4 blocks/CU (32-wave cap) vs r14's 3 at 35% measured.
// Adversarial halves > HCAP take a per-row global-scan slow path.
// ---------------------------------------------------------------------------
__global__ __launch_bounds__(GTHREADS) void region_sort_gather(
        const int* __restrict__ cCursor,
        const uint2* __restrict__ cCsr,
        const __half* __restrict__ xt,
        const float* __restrict__ bias,
        float* __restrict__ out, int M) {
    __shared__ uint2 sorted[HCAP];        // 22.5 KB
    __shared__ int whist[NGW][CROWS];     // 4 KB: counts -> abs cursors
    __shared__ int rowOff[CROWS];         // absolute exclusive row base
    __shared__ int rowCnt[CROWS];
    __shared__ int halfBase;              // rowOff[64]
    int c = blockIdx.x;
    int n = min(cCursor[c], CAP_C);
    int t = threadIdx.x;
    int w = t >> 6;                       // wave id 0..7
    uint2 ec[GEPT];
    for (int i = t; i < NGW * CROWS; i += GTHREADS) (&whist[0][0])[i] = 0;
    __syncthreads();
    const uint2* reg = cCsr + (size_t)c * CAP_C;
#pragma unroll
    for (int q = 0; q < GEPT; ++q) {
        int j = q * GTHREADS + t;
        if (j < n) {
            uint2 e = reg[j];
            ec[q] = e;
            atomicAdd(&whist[w][(e.x >> SRC_BITS) & (CROWS - 1)], 1);
        }
    }
    __syncthreads();
    int tot = 0;
    if (t < CROWS) {
#pragma unroll
        for (int w2 = 0; w2 < NGW; ++w2) tot += whist[w2][t];
        rowCnt[t] = tot;
        rowOff[t] = tot;
    }
    __syncthreads();
    for (int off = 1; off < CROWS; off <<= 1) {
        int add = (t < CROWS && t >= off) ? rowOff[t - off] : 0;
        __syncthreads();
        if (t < CROWS) rowOff[t] += add;
        __syncthreads();
    }
    if (t < CROWS) {
        int excl = rowOff[t] - rowCnt[t];
        rowOff[t] = excl;
        if (t == 64) halfBase = excl;     // = count of rows 0..63
        int run = excl;
#pragma unroll
        for (int w2 = 0; w2 < NGW; ++w2) {
            int cn = whist[w2][t];
            whist[w2][t] = run;           // absolute cursor for (wave,row)
            run += cn;
        }
    }
    __syncthreads();
    int g = t >> 5;                       // half-wave id 0..15
    int b = t & 31;                       // batch lane
    int half0 = halfBase;
    int half1 = n - halfBase;

    if (half0 <= HCAP && half1 <= HCAP) {
        for (int h = 0; h < 2; ++h) {
            int hb = h ? halfBase : 0;
            // scatter this half's entries into sorted[]
#pragma unroll
            for (int q = 0; q < GEPT; ++q) {
                int j = q * GTHREADS + t;
                if (j < n) {
                    int row = (ec[q].x >> SRC_BITS) & (CROWS - 1);
                    if ((row >> 6) == h) {
                        int p = atomicAdd(&whist[w][row], 1) - hb;
                        sorted[p] = ec[q];
                    }
                }
            }
            __syncthreads();
            // gather this half's 64 rows: 16 half-waves x 4 rows
            for (int r = (h << 6) + g; r < (h << 6) + 64; r += 16) {
                int m = c * CROWS + r;
                if (m >= M) continue;
                int jj   = rowOff[r] - hb;
                int jend = jj + rowCnt[r];
                float acc0 = 0.f, acc1 = 0.f;
                for (; jj + 8 <= jend; jj += 8) {
                    uint2 e0 = sorted[jj + 0];
                    uint2 e1 = sorted[jj + 1];
                    uint2 e2 = sorted[jj + 2];
                    uint2 e3 = sorted[jj + 3];
                    uint2 e4 = sorted[jj + 4];
                    uint2 e5 = sorted[jj + 5];
                    uint2 e6 = sorted[jj + 6];
                    uint2 e7 = sorted[jj + 7];
                    float x0 = __half2float(xt[(size_t)(e0.x & SRC_MASK) * NB + b]);
                    float x1 = __half2float(xt[(size_t)(e1.x & SRC_MASK) * NB + b]);
                    float x2 = __half2float(xt[(size_t)(e2.x & SRC_MASK) * NB + b]);
                    float x3 = __half2float(xt[(size_t)(e3.x & SRC_MASK) * NB + b]);
                    float x4 = __half2float(xt[(size_t)(e4.x & SRC_MASK) * NB + b]);
                    float x5 = __half2float(xt[(size_t)(e5.x & SRC_MASK) * NB + b]);
                    float x6 = __half2float(xt[(size_t)(e6.x & SRC_MASK) * NB + b]);
                    float x7 = __half2float(xt[(size_t)(e7.x & SRC_MASK) * NB + b]);
                    acc0 = fmaf(__uint_as_float(e0.y), x0, acc0);
                    acc1 = fmaf(__uint_as_float(e1.y), x1, acc1);
                    acc0 = fmaf(__uint_as_float(e2.y), x2, acc0);
                    acc1 = fmaf(__uint_as_float(e3.y), x3, acc1);
                    acc0 = fmaf(__uint_as_float(e4.y), x4, acc0);
                    acc1 = fmaf(__uint_as_float(e5.y), x5, acc1);
                    acc0 = fmaf(__uint_as_float(e6.y), x6, acc0);
                    acc1 = fmaf(__uint_as_float(e7.y), x7, acc1);
                }
                for (; jj < jend; ++jj) {
                    uint2 e = sorted[jj];
                    acc0 = fmaf(__uint_as_float(e.y),
                                __half2float(xt[(size_t)(e.x & SRC_MASK) * NB + b]),
                                acc0);
                }
                out[(size_t)b * M + m] = acc0 + acc1 + bias[m];
            }
            __syncthreads();   // protect sorted[] before next round
        }
    } else {
        // slow path (arbitrary skew): per-row scan of the L2-resident region
        for (int r = g; r < CROWS; r += 16) {
            int m = c * CROWS + r;
            if (m >= M) continue;
            float acc = 0.f;
            for (int j = 0; j < n; ++j) {
                uint2 e = reg[j];
                if ((int)((e.x >> SRC_BITS) & (CROWS - 1)) == r)
                    acc = fmaf(__uint_as_float(e.y),
                               __half2float(xt[(size_t)(e.x & SRC_MASK) * NB + b]),
                               acc);
            }
            out[(size_t)b * M + m] = acc + bias[m];
        }
    }
}

// ---------------------------------------------------------------------------
// Fixup: apply overflow edges (statistically zero) with global atomics
// into out (B, M). Runs AFTER region_sort_gather.
// ---------------------------------------------------------------------------
__global__ void fixup_kernel(const int* __restrict__ ovCount,
                             const int* __restrict__ ovList,
                             const int* __restrict__ src,
                             const int* __restrict__ dst,
                             const float* __restrict__ vals,
                             const __half* __restrict__ xt,
                             float* __restrict__ out, int M) {
    long long total = (long long)(*ovCount) * 32;
    long long stride = (long long)gridDim.x * blockDim.x;
    for (long long i = (long long)blockIdx.x * blockDim.x + threadIdx.x;
         i < total; i += stride) {
        int k = (int)(i >> 5);
        int b = (int)(i & 31);
        int e = ovList[k];
        atomicAdd(&out[(size_t)b * M + dst[e]],
                  vals[e] * __half2float(xt[(size_t)src[e] * NB + b]));
    }
}

// ---------------------------------------------------------------------------
// yt (M, B) -> out (B, M), + bias (fallback path only).
// ---------------------------------------------------------------------------
__global__ void finalize_kernel(const float* __restrict__ yt,
                                const float* __restrict__ bias,
                                float* __restrict__ out, int M) {
    __shared__ float tile[32][33];
    int m0 = blockIdx.x * 32;
    for (int i = threadIdx.y; i < 32; i += 8) {
        int m = m0 + i;
        tile[i][threadIdx.x] = (m < M) ? yt[(size_t)m * NB + threadIdx.x] : 0.f;
    }
    __syncthreads();
    for (int i = threadIdx.y; i < 32; i += 8) {
        int m = m0 + threadIdx.x;
        if (m < M) out[(size_t)i * M + m] = tile[threadIdx.x][i] + bias[m];
    }
}

// ---------------------------------------------------------------------------
// Fallback: global-atomic scatter (needs only xt + yt).
// ---------------------------------------------------------------------------
__global__ void scatter_kernel(const int* __restrict__ src,
                               const int* __restrict__ dst,
                               const float* __restrict__ vals,
                               const __half* __restrict__ xt,
                               float* __restrict__ yt, int nnz) {
    long long tid = (long long)blockIdx.x * blockDim.x + threadIdx.x;
    int e = (int)(tid >> 5);
    if (e >= nnz) return;
    int b = (int)(tid & 31);
    atomicAdd(&yt[(size_t)dst[e] * NB + b],
              vals[e] * __half2float(xt[(size_t)src[e] * NB + b]));
}

extern "C" void kernel_launch(void* const* d_in, const int* in_sizes, int n_in,
                              void* d_out, int out_size, void* d_ws, size_t ws_size,
                              hipStream_t stream) {
    const float* x       = (const float*)d_in[0];   // (B, N, 1) fp32
    const int*   indices = (const int*)  d_in[1];   // (2, NNZ) int32
    const float* vals    = (const float*)d_in[2];   // (NNZ,) fp32
    const float* bias    = (const float*)d_in[3];   // (M, 1) fp32

    float* out = (float*)d_out;                     // (B, M, 1) fp32

    int nnz = in_sizes[1] / 2;
    int N   = in_sizes[0] / NB;
    int M   = in_sizes[3];

    const int* src = indices;        // row 0
    const int* dst = indices + nnz;  // row 1

    int ncoarse = (M + CROWS - 1) >> CSHIFT;   // 782 for M=100000

    // primary workspace layout (~48 MB):
    //   xt       N*NB f16                (6.4 MB)
    //   cCursor  NC_MAX i32              | zeroed by transpose block 0
    //   ovCount  4 i32                   |
    //   ovList   nnz i32                 (12.8 MB)
    //   cCsr     ncoarse*CAP_C uint2     (28.8 MB)
    __half* xt      = (__half*)d_ws;
    int*    cCursor = (int*)(xt + (size_t)N * NB);
    int*    ovCount = cCursor + NC_MAX;
    int*    ovList  = ovCount + 4;
    uint2*  cCsr    = (uint2*)(((uintptr_t)(ovList + nnz) + 15) &
                               ~(uintptr_t)15);

    size_t need = (size_t)((char*)(cCsr + (size_t)ncoarse * CAP_C) -
                           (char*)d_ws);

    // fallback layout: yt immediately after xt (paths are exclusive)
    float* yt = (float*)(xt + (size_t)N * NB);
    size_t need_fb = (size_t)((char*)(yt + (size_t)M * NB) - (char*)d_ws);

    if (ws_size >= need && ncoarse <= NC_MAX) {
        transpose_x_kernel<<<(N + 31) / 32, dim3(32, 8), 0, stream>>>(
            x, xt, cCursor, N);
        int fgrid = (nnz + FCHUNK - 1) / FCHUNK;  // 391
        fill_coarse<<<fgrid, FTHREADS, 0, stream>>>(src, dst, vals, cCursor,
                                                    cCsr, ovCount, ovList,
                                                    nnz);
        region_sort_gather<<<ncoarse, GTHREADS, 0, stream>>>(cCursor, cCsr,
                                                             xt, bias, out, M);
        fixup_kernel<<<32, 256, 0, stream>>>(ovCount, ovList, src, dst, vals,
                                             xt, out, M);
    } else if (ws_size >= need_fb) {
        transpose_x_kernel<<<(N + 31) / 32, dim3(32, 8), 0, stream>>>(
            x, xt, cCursor, N);  // zeroRegion overlaps yt start; harmless
        hipMemsetAsync(yt, 0, (size_t)M * NB * sizeof(float), stream);
        long long pairs = (long long)nnz * NB;
        int grid = (int)((pairs + 255) / 256);
        scatter_kernel<<<grid, 256, 0, stream>>>(src, dst, vals, xt, yt, nnz);
        finalize_kernel<<<(M + 31) / 32, dim3(32, 8), 0, stream>>>(yt, bias,
                                                                   out, M);
    }
}